// Round 4
// baseline (373.298 us; speedup 1.0000x reference)
//
#include <hip/hip_runtime.h>

#define NB 256              // histogram bins
#define NCH 48              // B*C = 16*3
#define HW (1024*1024)      // elements per channel
#define WPC (HW / 4)        // packed words per channel = 262144
#define THREADS 256
#define BPC 64              // blocks per channel -> 3072 blocks per big kernel
#define N4 (WPC / BPC)      // packed words per block = 4096
#define NTILE (N4 / (4 * THREADS))   // 4 uint4-tiles of 1024 words per block

// R4: same barrier-free three-dispatch pipeline as R3, but q is moved at
// 16 B/lane instead of 4 B/lane.
//   R3 post-mortem: measured region = harness ws-poison fill (768 MiB,
//   ~122 us, uncontrollable) + our kernels (~150 us inferred, vs 76 us
//   traffic floor). The q intermediate was the only non-16B global access:
//   scalar 4 B stores (K1) and loads (K3) -> 4x issue slots + sub-line
//   store granularity on 2 x 48 MB.
//   Fix: tile-transposed q layout. Within each 1024-word tile, thread t
//   packs the 4 words it produced from unit-stride float4 loads
//   {k*256+t} into ONE uint4 at word offset 4t. K3 reads the same uint4
//   and writes 4 unit-stride float4. All global traffic is now 16 B/lane.

__device__ __forceinline__ int quant255(float v) {
    v = fminf(fmaxf(v, 0.0f), 1.0f);
    int q = (int)(v * 255.0f);     // fp32 mul + trunc, same as jnp
    q = q < 0 ? 0 : q;
    q = q > 255 ? 255 : q;
    return q;
}

// ---------------- K1: quantize + per-block LDS hist -> global hist --------
__global__ __launch_bounds__(THREADS, 8) void hist_quant_kernel(
    const float* __restrict__ x, unsigned int* __restrict__ ghist,
    unsigned int* __restrict__ q) {
    __shared__ unsigned int lh[4 * NB];   // one 256-bin sub-hist per wave
    const int t = threadIdx.x;
    const int w = t >> 6;
    for (int i = t; i < 4 * NB; i += THREADS) lh[i] = 0u;
    __syncthreads();

    const int ch  = blockIdx.x / BPC;
    const int blk = blockIdx.x % BPC;
    const float4* xp = (const float4*)x + (size_t)ch * WPC;
    unsigned int* qp = q + (size_t)ch * WPC;
    const int base = blk * N4;

    for (int tile = 0; tile < NTILE; ++tile) {
        const int tb = base + tile * (4 * THREADS);
        unsigned pw[4];
        #pragma unroll
        for (int k = 0; k < 4; ++k) {
            float4 v = xp[tb + k * THREADS + t];
            int q0 = quant255(v.x), q1 = quant255(v.y);
            int q2 = quant255(v.z), q3 = quant255(v.w);
            atomicAdd(&lh[w * NB + q0], 1u);
            atomicAdd(&lh[w * NB + q1], 1u);
            atomicAdd(&lh[w * NB + q2], 1u);
            atomicAdd(&lh[w * NB + q3], 1u);
            pw[k] = (unsigned)q0 | ((unsigned)q1 << 8)
                  | ((unsigned)q2 << 16) | ((unsigned)q3 << 24);
        }
        // one 16 B unit-stride store: tile-transposed q layout
        ((uint4*)(qp + tb))[t] = make_uint4(pw[0], pw[1], pw[2], pw[3]);
    }
    __syncthreads();
    unsigned int s = lh[t] + lh[NB + t] + lh[2 * NB + t] + lh[3 * NB + t];
    if (s) atomicAdd(&ghist[ch * NB + t], s);
}

// ---------------- K2: per-channel CDF scan -> normalized LUT --------------
__global__ __launch_bounds__(THREADS) void lut_build_kernel(
    const unsigned int* __restrict__ ghist, float* __restrict__ lutg) {
    __shared__ float sbuf[NB];
    const int t  = threadIdx.x;
    const int ch = blockIdx.x;
    sbuf[t] = (float)ghist[ch * NB + t];   // ints < 2^24 -> exact fp32
    __syncthreads();
    for (int off = 1; off < NB; off <<= 1) {
        float add = (t >= off) ? sbuf[t - off] : 0.0f;
        __syncthreads();
        sbuf[t] += add;
        __syncthreads();
    }
    float total = sbuf[NB - 1];
    lutg[ch * NB + t] = sbuf[t] / fmaxf(total, 1.0f);
}

// ---------------- K3: remap packed q through LUT -> y ---------------------
__global__ __launch_bounds__(THREADS, 8) void remap_kernel(
    const unsigned int* __restrict__ q, const float* __restrict__ lutg,
    float* __restrict__ y) {
    __shared__ float lut[NB];
    const int t   = threadIdx.x;
    const int ch  = blockIdx.x / BPC;
    const int blk = blockIdx.x % BPC;

    lut[t] = lutg[ch * NB + t];            // THREADS == NB: one load each
    __syncthreads();

    const unsigned int* qp = q + (size_t)ch * WPC;
    float4*             yp = (float4*)y + (size_t)ch * WPC;
    const int base = blk * N4;

    for (int tile = 0; tile < NTILE; ++tile) {
        const int tb = base + tile * (4 * THREADS);
        uint4 pk = ((const uint4*)(qp + tb))[t];   // 16 B unit-stride load
        unsigned pw[4] = {pk.x, pk.y, pk.z, pk.w};
        #pragma unroll
        for (int k = 0; k < 4; ++k) {
            unsigned p = pw[k];
            yp[tb + k * THREADS + t] =
                make_float4(lut[p & 255], lut[(p >> 8) & 255],
                            lut[(p >> 16) & 255], lut[p >> 24]);
        }
    }
}

extern "C" void kernel_launch(void* const* d_in, const int* in_sizes, int n_in,
                              void* d_out, int out_size, void* d_ws, size_t ws_size,
                              hipStream_t stream) {
    const float* x = (const float*)d_in[0];
    float* y = (float*)d_out;

    unsigned int* ghist = (unsigned int*)d_ws;                        // 48 KB
    float*        lutg  = (float*)((char*)d_ws + 64 * 1024);          // 48 KB
    unsigned int* q     = (unsigned int*)((char*)d_ws + 256 * 1024);  // 48 MB

    // zero ghist (ws is 0xAA-poisoned before every launch)
    hipMemsetAsync(d_ws, 0, 48 * 1024, stream);

    hist_quant_kernel<<<NCH * BPC, THREADS, 0, stream>>>(x, ghist, q);
    lut_build_kernel <<<NCH,       THREADS, 0, stream>>>(ghist, lutg);
    remap_kernel     <<<NCH * BPC, THREADS, 0, stream>>>(q, lutg, y);
}

// Round 6
// 333.599 us; speedup vs baseline: 1.1190x; 1.1190x over previous
//
#include <hip/hip_runtime.h>

#define NB 256              // histogram bins
#define NCH 48              // B*C = 16*3
#define HW (1024*1024)      // elements per channel
#define WPC (HW / 4)        // packed words per channel = 262144
#define THREADS 256
#define BPC 64              // blocks per channel -> 3072 blocks per big kernel
#define N4 (WPC / BPC)      // packed words per block = 4096
#define NTILE (N4 / (4 * THREADS))   // 4 uint4-tiles of 1024 words per block

// Native clang vector types: __builtin_nontemporal_* rejects
// HIP_vector_type (R5 compile failure), but accepts ext_vector_type.
typedef float  nf4 __attribute__((ext_vector_type(4)));
typedef unsigned int nu4 __attribute__((ext_vector_type(4)));

// R6 = R5 retry: two-dispatch pipeline with L3-aware cache policy.
//   R4 post-mortem: three-pass kernels total ~150 us vs 76 us traffic
//   floor; the harness's 768 MiB 0xAA ws-poison fill leaves dirty poison
//   lines in the 256 MiB L3, so every allocating miss forces a poison
//   writeback, and our once-used x/y lines evict the q intermediate.
//   Changes vs R4:
//     * K1 x loads  = nontemporal (read-once: no L3 allocation)
//     * K3 y stores = nontemporal (write-once: stream out, keep q in L3)
//     * q stays cacheable both ways -> K3's q reads should be L3 hits
//     * K2 folded into K3: every block re-scans ghist (256 ints,
//       overlapped across 3072 blocks) -> one fewer dispatch, no lutg.

__device__ __forceinline__ int quant255(float v) {
    v = fminf(fmaxf(v, 0.0f), 1.0f);
    int q = (int)(v * 255.0f);     // fp32 mul + trunc, same as jnp
    q = q < 0 ? 0 : q;
    q = q > 255 ? 255 : q;
    return q;
}

// ---------------- K1: quantize + per-block LDS hist -> global hist --------
__global__ __launch_bounds__(THREADS, 8) void hist_quant_kernel(
    const float* __restrict__ x, unsigned int* __restrict__ ghist,
    unsigned int* __restrict__ q) {
    __shared__ unsigned int lh[4 * NB];   // one 256-bin sub-hist per wave
    const int t = threadIdx.x;
    const int w = t >> 6;
    for (int i = t; i < 4 * NB; i += THREADS) lh[i] = 0u;
    __syncthreads();

    const int ch  = blockIdx.x / BPC;
    const int blk = blockIdx.x % BPC;
    const nf4* xp = (const nf4*)x + (size_t)ch * WPC;
    unsigned int* qp = q + (size_t)ch * WPC;
    const int base = blk * N4;

    for (int tile = 0; tile < NTILE; ++tile) {
        const int tb = base + tile * (4 * THREADS);
        unsigned pw[4];
        #pragma unroll
        for (int k = 0; k < 4; ++k) {
            // nontemporal: x is read exactly once across the whole pipeline
            nf4 v = __builtin_nontemporal_load(xp + tb + k * THREADS + t);
            int q0 = quant255(v.x), q1 = quant255(v.y);
            int q2 = quant255(v.z), q3 = quant255(v.w);
            atomicAdd(&lh[w * NB + q0], 1u);
            atomicAdd(&lh[w * NB + q1], 1u);
            atomicAdd(&lh[w * NB + q2], 1u);
            atomicAdd(&lh[w * NB + q3], 1u);
            pw[k] = (unsigned)q0 | ((unsigned)q1 << 8)
                  | ((unsigned)q2 << 16) | ((unsigned)q3 << 24);
        }
        // one 16 B unit-stride CACHEABLE store: q should stay L3-resident
        ((uint4*)(qp + tb))[t] = make_uint4(pw[0], pw[1], pw[2], pw[3]);
    }
    __syncthreads();
    unsigned int s = lh[t] + lh[NB + t] + lh[2 * NB + t] + lh[3 * NB + t];
    if (s) atomicAdd(&ghist[ch * NB + t], s);
}

// ---------------- K3: scan ghist (per block) + remap q -> y ---------------
__global__ __launch_bounds__(THREADS, 8) void remap_kernel(
    const unsigned int* __restrict__ q, const unsigned int* __restrict__ ghist,
    float* __restrict__ y) {
    __shared__ float sbuf[NB];
    __shared__ float lut[NB];
    const int t   = threadIdx.x;
    const int ch  = blockIdx.x / BPC;
    const int blk = blockIdx.x % BPC;

    // Per-block CDF scan (folded former K2): 256 ints, L2-hot
    sbuf[t] = (float)ghist[ch * NB + t];   // ints < 2^24 -> exact fp32
    __syncthreads();
    for (int off = 1; off < NB; off <<= 1) {
        float add = (t >= off) ? sbuf[t - off] : 0.0f;
        __syncthreads();
        sbuf[t] += add;
        __syncthreads();
    }
    float total = sbuf[NB - 1];
    lut[t] = sbuf[t] / fmaxf(total, 1.0f);
    __syncthreads();

    const unsigned int* qp = q + (size_t)ch * WPC;
    nf4*                yp = (nf4*)y + (size_t)ch * WPC;
    const int base = blk * N4;

    for (int tile = 0; tile < NTILE; ++tile) {
        const int tb = base + tile * (4 * THREADS);
        uint4 pk = ((const uint4*)(qp + tb))[t];   // cacheable: L3 hit
        unsigned pw[4] = {pk.x, pk.y, pk.z, pk.w};
        #pragma unroll
        for (int k = 0; k < 4; ++k) {
            unsigned p = pw[k];
            nf4 o;
            o.x = lut[p & 255];
            o.y = lut[(p >> 8) & 255];
            o.z = lut[(p >> 16) & 255];
            o.w = lut[p >> 24];
            // nontemporal: y is write-once, stream past L3
            __builtin_nontemporal_store(o, yp + tb + k * THREADS + t);
        }
    }
}

extern "C" void kernel_launch(void* const* d_in, const int* in_sizes, int n_in,
                              void* d_out, int out_size, void* d_ws, size_t ws_size,
                              hipStream_t stream) {
    const float* x = (const float*)d_in[0];
    float* y = (float*)d_out;

    unsigned int* ghist = (unsigned int*)d_ws;                        // 48 KB
    unsigned int* q     = (unsigned int*)((char*)d_ws + 256 * 1024);  // 48 MB

    // zero ghist (ws is 0xAA-poisoned before every launch)
    (void)hipMemsetAsync(d_ws, 0, 48 * 1024, stream);

    hist_quant_kernel<<<NCH * BPC, THREADS, 0, stream>>>(x, ghist, q);
    remap_kernel     <<<NCH * BPC, THREADS, 0, stream>>>(q, ghist, y);
}